// Round 2
// baseline (313.641 us; speedup 1.0000x reference)
//
#include <hip/hip_runtime.h>

// ---------- constants ----------
#define B_   16
#define C_   256
#define OC_  256
#define H_   64
#define W_   64

typedef __attribute__((ext_vector_type(8))) __bf16 bf16x8;
typedef __attribute__((ext_vector_type(4))) float  f32x4;

__device__ __forceinline__ short f2bf(float f) {
    unsigned u = __float_as_uint(f);
    u += 0x7fffu + ((u >> 16) & 1u);
    return (short)(u >> 16);
}
__device__ __forceinline__ unsigned pk2(float a, float b) {
    return (unsigned(f2bf(a)) & 0xffffu) | (unsigned(f2bf(b)) << 16);
}
__device__ __forceinline__ void gll16(const void* g, void* l) {
    __builtin_amdgcn_global_load_lds(
        (const __attribute__((address_space(1))) unsigned int*)g,
        (__attribute__((address_space(3))) unsigned int*)l,
        16, 0, 0);
}

// ---------- kernel 1: x (fp32, NCHW) -> x_t (bf16, [b][y][x][c]) + pooled atomics ----------
__global__ __launch_bounds__(256) void k_transpose_pool(
        const float* __restrict__ x, short* __restrict__ xt, float* __restrict__ pooled) {
    int y = blockIdx.x, b = blockIdx.y, t = threadIdx.x;
    int si = y >> 4;
    int lane = t & 63, wv = t >> 6;
    int xq = lane & 15, cw = lane >> 4;
    __shared__ float tile[64 * 67];   // stride 67: both phases ~2-way (free)

    for (int cc = 0; cc < 4; ++cc) {
        int cbase = cc * 64;
        if (cc) __syncthreads();
        #pragma unroll
        for (int r = 0; r < 4; ++r) {
            int c_l = r * 16 + wv * 4 + cw;
            float4 v = *(const float4*)&x[(((size_t)b * C_ + cbase + c_l) * H_ + y) * W_ + xq * 4];
            float* tp = &tile[c_l * 67 + xq * 4];
            tp[0] = v.x; tp[1] = v.y; tp[2] = v.z; tp[3] = v.w;
            float s = v.x + v.y + v.z + v.w;       // pooling partial (4 x)
            s += __shfl_xor(s, 1);
            s += __shfl_xor(s, 2);
            if ((lane & 3) == 0)
                atomicAdd(&pooled[((b * 4 + si) * 4 + (xq >> 2)) * 256 + cbase + c_l], s);
        }
        __syncthreads();
        #pragma unroll
        for (int r2 = 0; r2 < 2; ++r2) {
            int u = r2 * 256 + t;
            int xx = u >> 3, cgl = u & 7;
            float f[8];
            #pragma unroll
            for (int j = 0; j < 8; ++j) f[j] = tile[(cgl * 8 + j) * 67 + xx];
            uint4 pkv;
            pkv.x = pk2(f[0], f[1]); pkv.y = pk2(f[2], f[3]);
            pkv.z = pk2(f[4], f[5]); pkv.w = pk2(f[6], f[7]);
            *(uint4*)&xt[(((size_t)b * H_ + y) * W_ + xx) * C_ + cbase + cgl * 8] = pkv;
        }
    }
}

// ---------- kernel 2: routing head -> r[b][k][c] ----------
__global__ __launch_bounds__(256) void k_route(
        const float* __restrict__ pooled, const float* __restrict__ rconv_w,
        const float* __restrict__ rconv_b, const float* __restrict__ fc_w,
        const float* __restrict__ fc_b, float* __restrict__ r_buf) {
    int b = blockIdx.x;
    int t = threadIdx.x;
    __shared__ float pl[16][257];
    __shared__ float y1[256];

    #pragma unroll
    for (int q = 0; q < 16; ++q)
        pl[q][t] = pooled[b * 4096 + q * 256 + t] * (1.0f / 256.0f);
    __syncthreads();
    {
        int rcc = t >> 4, ss = t & 15;
        float acc = rconv_b[rcc];
        #pragma unroll 8
        for (int c = 0; c < 256; ++c)
            acc += pl[ss][c] * rconv_w[rcc * 256 + c];
        y1[rcc * 16 + ss] = fmaxf(acc, 0.f);
    }
    __syncthreads();
    for (int e0 = 0; e0 < 768; e0 += 256) {
        int e = e0 + t;
        float acc = fc_b[e];
        #pragma unroll 8
        for (int q = 0; q < 256; ++q)
            acc += y1[q] * fc_w[(size_t)e * 256 + q];
        acc = fmaxf(acc, 0.f);
        r_buf[(size_t)b * 768 + e] = 1.f / (1.f + __expf(-acc));
    }
}

// ---------- kernel 3: combine experts -> wcomb[b][o][tap][c] (bf16) ----------
__global__ __launch_bounds__(256) void k_combine(
        const float* __restrict__ E, const float* __restrict__ r_buf,
        short* __restrict__ wcomb) {
    int o = blockIdx.x;        // 0..255
    int b0 = blockIdx.y * 4;   // 4 b's per block
    int t = threadIdx.x;
    __shared__ float eT[3][2304];
    #pragma unroll
    for (int k = 0; k < 3; ++k)
        #pragma unroll
        for (int q = 0; q < 9; ++q)
            eT[k][q * 256 + t] = E[((size_t)k * OC_ + o) * 2304 + q * 256 + t];
    __syncthreads();
    int c = t;
    #pragma unroll
    for (int bb = 0; bb < 4; ++bb) {
        int b = b0 + bb;
        float r0 = r_buf[(size_t)b * 768 + c];
        float r1 = r_buf[(size_t)b * 768 + 256 + c];
        float r2 = r_buf[(size_t)b * 768 + 512 + c];
        short* wo = wcomb + ((size_t)(b * OC_ + o) * 9) * C_;
        #pragma unroll
        for (int tap = 0; tap < 9; ++tap) {
            float v = r0 * eT[0][c * 9 + tap] + r1 * eT[1][c * 9 + tap]
                    + r2 * eT[2][c * 9 + tap];
            wo[tap * C_ + c] = f2bf(v);
        }
    }
}

// ---------- kernel 4: implicit-GEMM conv, A in registers (no abuf, no tap barriers) ----------
// R1 post-mortem: per-tap 2735 cyc = MFMA 1242 + LDS 1542 SERIALIZED by the
// tap-barrier lockstep (all waves read LDS together, then MFMA together).
// Fix: A (wcomb) is L2-hot -> load A-fragments global->register, 2-phase-deep
// ping-pong (P[2][4], issued right after each 16-MFMA cluster, consumed one
// full phase later). abuf deleted -> LDS read traffic halves (only win),
// per-tap barriers deleted (win is read-only within a cc) -> waves de-phase
// and LDS/MFMA/L2 overlap. LDS 32 KB, ~150 VGPR -> 3 blocks/CU.
__global__ __launch_bounds__(256, 3) void k_conv(
        const short* __restrict__ xt, const short* __restrict__ wcomb,
        float* __restrict__ out, const short* __restrict__ zbuf) {
    int lin  = blockIdx.x;
    int work = (lin & 7) * 128 + (lin >> 3);   // XCD-contiguous: 2 samples/XCD
    int b      = work >> 6;
    int o_base = ((work >> 5) & 1) * 128;
    int y0     = (work & 31) * 2;

    int t = threadIdx.x;
    int lane = t & 63, w = t >> 6;
    int quad = lane >> 4, l15 = lane & 15;

    __shared__ __align__(16) short win[4 * 64 * 64];   // [wrow][xc][slot8][8ch] 32 KB only

    // window staging sources (8 rounds x 256 threads = 2048 tasks, halo rows -> zbuf)
    const short* wsrc[8];
    #pragma unroll
    for (int r = 0; r < 8; ++r) {
        int u = r * 256 + t;
        int pos = u >> 3, sp = u & 7;
        int wrow = pos >> 6, xc = pos & 63;
        int yy = y0 - 1 + wrow;
        int ss = sp ^ (xc & 7);                 // XOR swizzle at source
        wsrc[r] = ((unsigned)yy < 64u)
            ? xt + (((size_t)b * 64 + yy) * 64 + xc) * 256 + ss * 8
            : zbuf;
    }

    int m_base = (w & 1) * 64;
    int n_base = (w >> 1) * 64;
    int ry0 = n_base >> 6;                       // output row within pair (0/1)

    // A base pointers per m-tile: lane reads row o_l = m_base+mb*16+l15,
    // channel quad*8 within the k-slot. Offsets tap*256 + cc*64 + s*32 (shorts).
    const short* pA[4];
    #pragma unroll
    for (int mb = 0; mb < 4; ++mb) {
        int o_l = m_base + mb * 16 + l15;
        pA[mb] = wcomb + ((size_t)(b * 256 + o_base + o_l) * 9) * 256 + quad * 8;
    }

    f32x4 acc[4][4];
    #pragma unroll
    for (int i = 0; i < 4; ++i)
        #pragma unroll
        for (int j = 0; j < 4; ++j) acc[i][j] = {0.f, 0.f, 0.f, 0.f};

    for (int cc = 0; cc < 4; ++cc) {
        int ccOff = cc * 64;
        // stage window (direct-to-LDS)
        #pragma unroll
        for (int r = 0; r < 8; ++r)
            gll16(wsrc[r] + ccOff, &win[(r * 256 + w * 64) * 8]);

        // preload A phases 0,1 (tap 0, s=0/1) into the ping-pong regs;
        // their latency hides under the staging drain below.
        bf16x8 P[2][4];
        #pragma unroll
        for (int mb = 0; mb < 4; ++mb) {
            P[0][mb] = *(const bf16x8*)(pA[mb] + ccOff);
            P[1][mb] = *(const bf16x8*)(pA[mb] + ccOff + 32);
        }
        __syncthreads();   // drains gll16 (win ready) + A preloads

        // 18 phases = 9 taps x 2 k-slots; no barriers inside.
        #pragma unroll
        for (int ph = 0; ph < 18; ++ph) {
            const int tp = ph >> 1, s = ph & 1;
            const int ti = tp / 3, tj = tp % 3;
            const int cur = ph & 1;              // P buffer parity
            int wrb = (ry0 + ti) * 4096;         // window row base (shorts)

            bf16x8 bv[4];
            #pragma unroll
            for (int nb = 0; nb < 4; ++nb) {
                int xc = nb * 16 + l15 + (tj - 1);
                bool ok = ((unsigned)xc < 64u);
                int xs = ok ? xc : 0;
                int slog = s * 4 + quad;
                bf16x8 v = *(const bf16x8*)&win[wrb + xs * 64 + ((slog ^ (xs & 7)) * 8)];
                bf16x8 zz = {};
                bv[nb] = ok ? v : zz;            // column halo is zero
            }
            __builtin_amdgcn_s_setprio(1);
            #pragma unroll
            for (int mb = 0; mb < 4; ++mb)
                #pragma unroll
                for (int nb = 0; nb < 4; ++nb)
                    acc[mb][nb] = __builtin_amdgcn_mfma_f32_16x16x32_bf16(
                        P[cur][mb], bv[nb], acc[mb][nb], 0, 0, 0);
            __builtin_amdgcn_s_setprio(0);

            // prefetch phase ph+2 into the buffer just consumed
            if (ph < 16) {
                const int np = ph + 2, ntp = np >> 1, ns = np & 1;
                #pragma unroll
                for (int mb = 0; mb < 4; ++mb)
                    P[cur][mb] = *(const bf16x8*)(pA[mb] + ntp * 256 + ccOff + ns * 32);
            }
        }
        if (cc < 3) __syncthreads();   // all win reads done before restage
    }

    #pragma unroll
    for (int mb = 0; mb < 4; ++mb) {
        #pragma unroll
        for (int nb = 0; nb < 4; ++nb) {
            int p  = n_base + nb * 16 + l15;
            int yy = y0 + (p >> 6);
            int xx = p & 63;
            #pragma unroll
            for (int rg = 0; rg < 4; ++rg) {
                int o = o_base + m_base + mb * 16 + quad * 4 + rg;
                out[(((size_t)b * OC_ + o) * H_ + yy) * W_ + xx] = acc[mb][nb][rg];
            }
        }
    }
}

// ---------- launcher ----------
extern "C" void kernel_launch(void* const* d_in, const int* in_sizes, int n_in,
                              void* d_out, int out_size, void* d_ws, size_t ws_size,
                              hipStream_t stream) {
    const float* x       = (const float*)d_in[0];
    const float* E       = (const float*)d_in[1];
    const float* rconv_w = (const float*)d_in[2];
    const float* rconv_b = (const float*)d_in[3];
    const float* fc_w    = (const float*)d_in[4];
    const float* fc_b    = (const float*)d_in[5];
    float* out = (float*)d_out;

    char* ws = (char*)d_ws;
    short* xt     = (short*)(ws);                    // 32 MiB
    short* wcomb  = (short*)(ws + 33554432);         // 18 MiB
    float* pooled = (float*)(ws + 52428800);         // 256 KiB
    short* zbuf   = (short*)(ws + 52690944);         // 1 KiB zeros (adjacent to pooled)
    float* rbuf   = (float*)(ws + 52692992);         // 48 KiB

    hipMemsetAsync(pooled, 0, 262144 + 1024, stream);   // pooled + zbuf in one node

    k_transpose_pool<<<dim3(64, 16), 256, 0, stream>>>(x, xt, pooled);
    k_route<<<dim3(16), 256, 0, stream>>>(pooled, rconv_w, rconv_b, fc_w, fc_b, rbuf);
    k_combine<<<dim3(256, 4), 256, 0, stream>>>(E, rbuf, wcomb);
    k_conv<<<dim3(1024), 256, 0, stream>>>(xt, wcomb, out, zbuf);
}

// Round 3
// 252.767 us; speedup vs baseline: 1.2408x; 1.2408x over previous
//
#include <hip/hip_runtime.h>

// ---------- constants ----------
#define B_   16
#define C_   256
#define OC_  256
#define H_   64
#define W_   64

typedef __attribute__((ext_vector_type(8))) __bf16 bf16x8;
typedef __attribute__((ext_vector_type(4))) float  f32x4;

__device__ __forceinline__ short f2bf(float f) {
    unsigned u = __float_as_uint(f);
    u += 0x7fffu + ((u >> 16) & 1u);
    return (short)(u >> 16);
}
__device__ __forceinline__ unsigned pk2(float a, float b) {
    return (unsigned(f2bf(a)) & 0xffffu) | (unsigned(f2bf(b)) << 16);
}
__device__ __forceinline__ void gll16(const void* g, void* l) {
    __builtin_amdgcn_global_load_lds(
        (const __attribute__((address_space(1))) unsigned int*)g,
        (__attribute__((address_space(3))) unsigned int*)l,
        16, 0, 0);
}

// ---------- kernel 1: x (fp32, NCHW) -> x_t (bf16, [b][y][x][c]) + pooled atomics ----------
__global__ __launch_bounds__(256) void k_transpose_pool(
        const float* __restrict__ x, short* __restrict__ xt, float* __restrict__ pooled) {
    int y = blockIdx.x, b = blockIdx.y, t = threadIdx.x;
    int si = y >> 4;
    int lane = t & 63, wv = t >> 6;
    int xq = lane & 15, cw = lane >> 4;
    __shared__ float tile[64 * 67];   // stride 67: both phases ~2-way (free)

    for (int cc = 0; cc < 4; ++cc) {
        int cbase = cc * 64;
        if (cc) __syncthreads();
        #pragma unroll
        for (int r = 0; r < 4; ++r) {
            int c_l = r * 16 + wv * 4 + cw;
            float4 v = *(const float4*)&x[(((size_t)b * C_ + cbase + c_l) * H_ + y) * W_ + xq * 4];
            float* tp = &tile[c_l * 67 + xq * 4];
            tp[0] = v.x; tp[1] = v.y; tp[2] = v.z; tp[3] = v.w;
            float s = v.x + v.y + v.z + v.w;       // pooling partial (4 x)
            s += __shfl_xor(s, 1);
            s += __shfl_xor(s, 2);
            if ((lane & 3) == 0)
                atomicAdd(&pooled[((b * 4 + si) * 4 + (xq >> 2)) * 256 + cbase + c_l], s);
        }
        __syncthreads();
        #pragma unroll
        for (int r2 = 0; r2 < 2; ++r2) {
            int u = r2 * 256 + t;
            int xx = u >> 3, cgl = u & 7;
            float f[8];
            #pragma unroll
            for (int j = 0; j < 8; ++j) f[j] = tile[(cgl * 8 + j) * 67 + xx];
            uint4 pkv;
            pkv.x = pk2(f[0], f[1]); pkv.y = pk2(f[2], f[3]);
            pkv.z = pk2(f[4], f[5]); pkv.w = pk2(f[6], f[7]);
            *(uint4*)&xt[(((size_t)b * H_ + y) * W_ + xx) * C_ + cbase + cgl * 8] = pkv;
        }
    }
}

// ---------- kernel 2: routing head -> r[b][k][c] ----------
__global__ __launch_bounds__(256) void k_route(
        const float* __restrict__ pooled, const float* __restrict__ rconv_w,
        const float* __restrict__ rconv_b, const float* __restrict__ fc_w,
        const float* __restrict__ fc_b, float* __restrict__ r_buf) {
    int b = blockIdx.x;
    int t = threadIdx.x;
    __shared__ float pl[16][257];
    __shared__ float y1[256];

    #pragma unroll
    for (int q = 0; q < 16; ++q)
        pl[q][t] = pooled[b * 4096 + q * 256 + t] * (1.0f / 256.0f);
    __syncthreads();
    {
        int rcc = t >> 4, ss = t & 15;
        float acc = rconv_b[rcc];
        #pragma unroll 8
        for (int c = 0; c < 256; ++c)
            acc += pl[ss][c] * rconv_w[rcc * 256 + c];
        y1[rcc * 16 + ss] = fmaxf(acc, 0.f);
    }
    __syncthreads();
    for (int e0 = 0; e0 < 768; e0 += 256) {
        int e = e0 + t;
        float acc = fc_b[e];
        #pragma unroll 8
        for (int q = 0; q < 256; ++q)
            acc += y1[q] * fc_w[(size_t)e * 256 + q];
        acc = fmaxf(acc, 0.f);
        r_buf[(size_t)b * 768 + e] = 1.f / (1.f + __expf(-acc));
    }
}

// ---------- kernel 3: combine experts -> wcomb[b][o][tap][c] (bf16) ----------
__global__ __launch_bounds__(256) void k_combine(
        const float* __restrict__ E, const float* __restrict__ r_buf,
        short* __restrict__ wcomb) {
    int o = blockIdx.x;        // 0..255
    int b0 = blockIdx.y * 4;   // 4 b's per block
    int t = threadIdx.x;
    __shared__ float eT[3][2304];
    #pragma unroll
    for (int k = 0; k < 3; ++k)
        #pragma unroll
        for (int q = 0; q < 9; ++q)
            eT[k][q * 256 + t] = E[((size_t)k * OC_ + o) * 2304 + q * 256 + t];
    __syncthreads();
    int c = t;
    #pragma unroll
    for (int bb = 0; bb < 4; ++bb) {
        int b = b0 + bb;
        float r0 = r_buf[(size_t)b * 768 + c];
        float r1 = r_buf[(size_t)b * 768 + 256 + c];
        float r2 = r_buf[(size_t)b * 768 + 512 + c];
        short* wo = wcomb + ((size_t)(b * OC_ + o) * 9) * C_;
        #pragma unroll
        for (int tap = 0; tap < 9; ++tap) {
            float v = r0 * eT[0][c * 9 + tap] + r1 * eT[1][c * 9 + tap]
                    + r2 * eT[2][c * 9 + tap];
            wo[tap * C_ + c] = f2bf(v);
        }
    }
}

// ---------- kernel 4: implicit-GEMM conv, 8-wave 8-phase-template port ----------
// R2 post-mortem: A global->reg is a 16-line gather -> latency wall. Revert to
// LDS-staged A. R0/R1 were the serial 2-phase structure (LDS 1536 + MFMA 1242
// = 2735 cyc/tap measured). This round ports the PROVEN m201 schedule shape:
// 512 threads (8 waves = the quadrant where T3/T4/T5 pay; 4-wave was null),
// block tile 128o x 256pos, win double-buffered (2x48KB, 6 rows) + A 3-buf
// rotation (48KB) = 144KB LDS -> 1 block/CU. Per phase (= one 16-MFMA
// cluster): [vmcnt(K) at tap bound][s_barrier][8 ds_read_b128][issue 1-3
// gll16][setprio(1) MFMA setprio(0)]. Staging spread 1 A-load/thread/phase,
// win(cc+1) bundles at phases 6/8/10. vmcnt never 0 except the final tap.
__global__ __launch_bounds__(512, 2) void k_conv(
        const short* __restrict__ xt, const short* __restrict__ wcomb,
        float* __restrict__ out, const short* __restrict__ zbuf) {
    int lin  = blockIdx.x;
    int work = (lin & 7) * 64 + (lin >> 3);   // XCD-contiguous: 2 samples/XCD
    int b      = work >> 5;
    int o_base = ((work >> 4) & 1) * 128;
    int y0     = (work & 15) * 4;             // 4 output rows per block

    int t = threadIdx.x;
    int lane = t & 63, w = t >> 6;            // w in 0..7
    int quad = lane >> 4, l15 = lane & 15;

    __shared__ __align__(16) short win2[2][6 * 64 * 64];   // 2 x 48 KB: rows y0-1..y0+4
    __shared__ __align__(16) short abuf[3][128 * 64];      // 3 x 16 KB tap rotation

    // window staging sources: 6 gll16 per thread per cc (3072 tasks)
    const short* wsrc[6];
    #pragma unroll
    for (int r = 0; r < 6; ++r) {
        int u = r * 512 + t;
        int pos = u >> 3, sp = u & 7;
        int wrow = pos >> 6, xc = pos & 63;
        int yy = y0 - 1 + wrow;
        int ss = sp ^ (xc & 7);                 // XOR swizzle at source
        wsrc[r] = ((unsigned)yy < 64u)
            ? xt + (((size_t)b * 64 + yy) * 64 + xc) * 256 + ss * 8
            : zbuf;
    }
    // A staging sources: 2 gll16 per thread per tap (1024 tasks)
    const short* asrc[2];
    #pragma unroll
    for (int r = 0; r < 2; ++r) {
        int u = r * 512 + t;
        int o_l = u >> 3, sp = u & 7;
        int ss = sp ^ (o_l & 7);
        asrc[r] = wcomb + (((size_t)b * 256 + o_base + o_l) * 9) * 256 + ss * 8;
    }

    int m_base = (w & 1) * 64;
    int ry0    = w >> 1;                       // output row within quad (0..3)

    f32x4 acc[4][4];
    #pragma unroll
    for (int i = 0; i < 4; ++i)
        #pragma unroll
        for (int j = 0; j < 4; ++j) acc[i][j] = {0.f, 0.f, 0.f, 0.f};

    // ---- prologue: win(cc=0) oldest, then A(0), A(1) newest ----
    #pragma unroll
    for (int r = 0; r < 6; ++r)
        gll16(wsrc[r], &win2[0][(r * 512 + w * 64) * 8]);
    #pragma unroll
    for (int r = 0; r < 2; ++r)
        gll16(asrc[r], &abuf[0][(r * 512 + w * 64) * 8]);
    #pragma unroll
    for (int r = 0; r < 2; ++r)
        gll16(asrc[r] + 256, &abuf[1][(r * 512 + w * 64) * 8]);

    for (int cc = 0; cc < 4; ++cc) {
        const int ccOff = cc * 64;
        const short* wb = win2[cc & 1];
        short* wbn = win2[(cc & 1) ^ 1];

        #pragma unroll
        for (int ph = 0; ph < 18; ++ph) {
            const int tp = ph >> 1, s = ph & 1;
            const int ti = tp / 3, tj = tp % 3;

            // tap-boundary counted wait: K = loads issued after the needed set
            if (s == 0) {
                if (cc == 3 && tp == 8)
                    asm volatile("s_waitcnt vmcnt(0)" ::: "memory");
                else if (cc < 3 && tp >= 4 && tp <= 6)
                    asm volatile("s_waitcnt vmcnt(4)" ::: "memory");
                else
                    asm volatile("s_waitcnt vmcnt(2)" ::: "memory");
            }
            __builtin_amdgcn_s_barrier();

            // ---- ds_reads for this cluster (compiler schedules lgkmcnt) ----
            const short* ab = abuf[tp % 3];
            int slog = s * 4 + quad;
            bf16x8 af[4], bv[4];
            #pragma unroll
            for (int mb = 0; mb < 4; ++mb) {
                int o_l = m_base + mb * 16 + l15;
                af[mb] = *(const bf16x8*)&ab[o_l * 64 + ((slog ^ (o_l & 7)) * 8)];
            }
            int wrb = (ry0 + ti) * 4096;
            #pragma unroll
            for (int nb = 0; nb < 4; ++nb) {
                int xc = nb * 16 + l15 + (tj - 1);
                bool ok = ((unsigned)xc < 64u);
                int xs = ok ? xc : 0;
                bf16x8 v = *(const bf16x8*)&wb[wrb + xs * 64 + ((slog ^ (xs & 7)) * 8)];
                bf16x8 zz = {};
                bv[nb] = ok ? v : zz;            // column halo is zero
            }

            // ---- staging issue for this phase (1 A-load/thread, + win bundle) ----
            if (tp < 7) {                         // A(tp+2) -> abuf[(tp+2)%3]
                gll16(asrc[s] + (tp + 2) * 256 + ccOff,
                      &abuf[(tp + 2) % 3][(s * 512 + w * 64) * 8]);
            } else if (cc < 3) {                  // cross-cc: A(0'), A(1')
                if (tp == 7)
                    gll16(asrc[s] + (ccOff + 64),
                          &abuf[0][(s * 512 + w * 64) * 8]);
                else
                    gll16(asrc[s] + 256 + (ccOff + 64),
                          &abuf[1][(s * 512 + w * 64) * 8]);
            }
            if (cc < 3 && s == 0 && tp >= 3 && tp <= 5) {   // win(cc+1) bundles
                int r0 = (tp - 3) * 2;
                gll16(wsrc[r0]     + ccOff + 64, &wbn[(r0 * 512 + w * 64) * 8]);
                gll16(wsrc[r0 + 1] + ccOff + 64, &wbn[((r0 + 1) * 512 + w * 64) * 8]);
            }

            // ---- pure-MFMA cluster ----
            __builtin_amdgcn_s_setprio(1);
            #pragma unroll
            for (int mb = 0; mb < 4; ++mb)
                #pragma unroll
                for (int nb = 0; nb < 4; ++nb)
                    acc[mb][nb] = __builtin_amdgcn_mfma_f32_16x16x32_bf16(
                        af[mb], bv[nb], acc[mb][nb], 0, 0, 0);
            __builtin_amdgcn_s_setprio(0);
        }
    }

    #pragma unroll
    for (int mb = 0; mb < 4; ++mb) {
        #pragma unroll
        for (int nb = 0; nb < 4; ++nb) {
            int xx = nb * 16 + l15;
            int yy = y0 + ry0;
            #pragma unroll
            for (int rg = 0; rg < 4; ++rg) {
                int o = o_base + m_base + mb * 16 + quad * 4 + rg;
                out[(((size_t)b * OC_ + o) * H_ + yy) * W_ + xx] = acc[mb][nb][rg];
            }
        }
    }
}

// ---------- launcher ----------
extern "C" void kernel_launch(void* const* d_in, const int* in_sizes, int n_in,
                              void* d_out, int out_size, void* d_ws, size_t ws_size,
                              hipStream_t stream) {
    const float* x       = (const float*)d_in[0];
    const float* E       = (const float*)d_in[1];
    const float* rconv_w = (const float*)d_in[2];
    const float* rconv_b = (const float*)d_in[3];
    const float* fc_w    = (const float*)d_in[4];
    const float* fc_b    = (const float*)d_in[5];
    float* out = (float*)d_out;

    char* ws = (char*)d_ws;
    short* xt     = (short*)(ws);                    // 32 MiB
    short* wcomb  = (short*)(ws + 33554432);         // 18 MiB
    float* pooled = (float*)(ws + 52428800);         // 256 KiB
    short* zbuf   = (short*)(ws + 52690944);         // 1 KiB zeros (adjacent to pooled)
    float* rbuf   = (float*)(ws + 52692992);         // 48 KiB

    hipMemsetAsync(pooled, 0, 262144 + 1024, stream);   // pooled + zbuf in one node

    k_transpose_pool<<<dim3(64, 16), 256, 0, stream>>>(x, xt, pooled);
    k_route<<<dim3(16), 256, 0, stream>>>(pooled, rconv_w, rconv_b, fc_w, fc_b, rbuf);
    k_combine<<<dim3(256, 4), 256, 0, stream>>>(E, rbuf, wcomb);
    k_conv<<<dim3(512), 512, 0, stream>>>(xt, wcomb, out, zbuf);
}

// Round 4
// 251.374 us; speedup vs baseline: 1.2477x; 1.0055x over previous
//
#include <hip/hip_runtime.h>

// ---------- constants ----------
#define B_   16
#define C_   256
#define OC_  256
#define H_   64
#define W_   64

typedef __attribute__((ext_vector_type(8))) __bf16 bf16x8;
typedef __attribute__((ext_vector_type(4))) float  f32x4;

__device__ __forceinline__ short f2bf(float f) {
    unsigned u = __float_as_uint(f);
    u += 0x7fffu + ((u >> 16) & 1u);
    return (short)(u >> 16);
}
__device__ __forceinline__ unsigned pk2(float a, float b) {
    return (unsigned(f2bf(a)) & 0xffffu) | (unsigned(f2bf(b)) << 16);
}
__device__ __forceinline__ void gll16(const void* g, void* l) {
    __builtin_amdgcn_global_load_lds(
        (const __attribute__((address_space(1))) unsigned int*)g,
        (__attribute__((address_space(3))) unsigned int*)l,
        16, 0, 0);
}

// ---------- kernel 1: x (fp32, NCHW) -> x_t (bf16, [b][y][x][c]) + pooled atomics ----------
__global__ __launch_bounds__(256) void k_transpose_pool(
        const float* __restrict__ x, short* __restrict__ xt, float* __restrict__ pooled) {
    int y = blockIdx.x, b = blockIdx.y, t = threadIdx.x;
    int si = y >> 4;
    int lane = t & 63, wv = t >> 6;
    int xq = lane & 15, cw = lane >> 4;
    __shared__ float tile[64 * 67];   // stride 67: both phases ~2-way (free)

    for (int cc = 0; cc < 4; ++cc) {
        int cbase = cc * 64;
        if (cc) __syncthreads();
        #pragma unroll
        for (int r = 0; r < 4; ++r) {
            int c_l = r * 16 + wv * 4 + cw;
            float4 v = *(const float4*)&x[(((size_t)b * C_ + cbase + c_l) * H_ + y) * W_ + xq * 4];
            float* tp = &tile[c_l * 67 + xq * 4];
            tp[0] = v.x; tp[1] = v.y; tp[2] = v.z; tp[3] = v.w;
            float s = v.x + v.y + v.z + v.w;       // pooling partial (4 x)
            s += __shfl_xor(s, 1);
            s += __shfl_xor(s, 2);
            if ((lane & 3) == 0)
                atomicAdd(&pooled[((b * 4 + si) * 4 + (xq >> 2)) * 256 + cbase + c_l], s);
        }
        __syncthreads();
        #pragma unroll
        for (int r2 = 0; r2 < 2; ++r2) {
            int u = r2 * 256 + t;
            int xx = u >> 3, cgl = u & 7;
            float f[8];
            #pragma unroll
            for (int j = 0; j < 8; ++j) f[j] = tile[(cgl * 8 + j) * 67 + xx];
            uint4 pkv;
            pkv.x = pk2(f[0], f[1]); pkv.y = pk2(f[2], f[3]);
            pkv.z = pk2(f[4], f[5]); pkv.w = pk2(f[6], f[7]);
            *(uint4*)&xt[(((size_t)b * H_ + y) * W_ + xx) * C_ + cbase + cgl * 8] = pkv;
        }
    }
}

// ---------- kernel 2: routing head -> r[b][k][c] ----------
// R3 analysis: old version read fc_w columns at 1KB stride per thread
// (uncoalesced) with only 16 blocks. New: 64 blocks (4 e-slices per b),
// one wave per output e: coalesced row read + 64-lane butterfly reduce.
__global__ __launch_bounds__(256) void k_route(
        const float* __restrict__ pooled, const float* __restrict__ rconv_w,
        const float* __restrict__ rconv_b, const float* __restrict__ fc_w,
        const float* __restrict__ fc_b, float* __restrict__ r_buf) {
    int b = blockIdx.x >> 2;
    int slice = blockIdx.x & 3;
    int t = threadIdx.x;
    int lane = t & 63, wv = t >> 6;
    __shared__ float pl[16][257];
    __shared__ float y1[256];

    #pragma unroll
    for (int q = 0; q < 16; ++q)
        pl[q][t] = pooled[b * 4096 + q * 256 + t] * (1.0f / 256.0f);
    __syncthreads();
    {   // rconv + relu: redundant across the 4 slices (trivial cost)
        int rcc = t >> 4, ss = t & 15;
        float acc = rconv_b[rcc];
        #pragma unroll 8
        for (int c = 0; c < 256; ++c)
            acc += pl[ss][c] * rconv_w[rcc * 256 + c];
        y1[rcc * 16 + ss] = fmaxf(acc, 0.f);
    }
    __syncthreads();
    // fc: 192 outputs per block, 48 per wave
    #pragma unroll 4
    for (int i = 0; i < 48; ++i) {
        int e = slice * 192 + wv * 48 + i;
        const float* row = fc_w + (size_t)e * 256;
        float p = y1[lane]       * row[lane]
                + y1[lane + 64]  * row[lane + 64]
                + y1[lane + 128] * row[lane + 128]
                + y1[lane + 192] * row[lane + 192];
        #pragma unroll
        for (int d = 1; d < 64; d <<= 1)
            p += __shfl_xor(p, d);
        if (lane == 0) {
            float a = fmaxf(p + fc_b[e], 0.f);
            r_buf[(size_t)b * 768 + e] = 1.f / (1.f + __expf(-a));
        }
    }
}

// ---------- kernel 3: combine experts -> wcomb[b][o][tap][c] (bf16) ----------
__global__ __launch_bounds__(256) void k_combine(
        const float* __restrict__ E, const float* __restrict__ r_buf,
        short* __restrict__ wcomb) {
    int o = blockIdx.x;        // 0..255
    int b0 = blockIdx.y * 4;   // 4 b's per block
    int t = threadIdx.x;
    __shared__ float eT[3][2304];
    #pragma unroll
    for (int k = 0; k < 3; ++k)
        #pragma unroll
        for (int q = 0; q < 9; ++q)
            eT[k][q * 256 + t] = E[((size_t)k * OC_ + o) * 2304 + q * 256 + t];
    __syncthreads();
    int c = t;
    #pragma unroll
    for (int bb = 0; bb < 4; ++bb) {
        int b = b0 + bb;
        float r0 = r_buf[(size_t)b * 768 + c];
        float r1 = r_buf[(size_t)b * 768 + 256 + c];
        float r2 = r_buf[(size_t)b * 768 + 512 + c];
        short* wo = wcomb + ((size_t)(b * OC_ + o) * 9) * C_;
        #pragma unroll
        for (int tap = 0; tap < 9; ++tap) {
            float v = r0 * eT[0][c * 9 + tap] + r1 * eT[1][c * 9 + tap]
                    + r2 * eT[2][c * 9 + tap];
            wo[tap * C_ + c] = f2bf(v);
        }
    }
}

// ---------- kernel 4: implicit-GEMM conv, 4x8 wave tile (LDS traffic x0.75) ----------
// R0's proven schedule (per-tap A dbuf + syncthreads, 2 blk/CU) with wider
// wave tile: M=64 x N=128 per wave -> 12 ds_read_b128 per 32 MFMA (was 16
// per 32). Block = 128 o x 256 pos (4 output rows). Kernel LDS-pipe time
// model: 45us -> 34us vs MFMA 37us. win 6 rows (48KB) + A dbuf (2x16KB)
// = 80KB -> exactly 2 blocks/CU. Grid 512 = 2/CU, XCD-contiguous.
__global__ __launch_bounds__(256, 2) void k_conv(
        const short* __restrict__ xt, const short* __restrict__ wcomb,
        float* __restrict__ out, const short* __restrict__ zbuf) {
    int lin  = blockIdx.x;
    int work = (lin & 7) * 64 + (lin >> 3);   // XCD-contiguous: 2 samples/XCD
    int b      = work >> 5;
    int o_base = ((work >> 4) & 1) * 128;
    int y0     = (work & 15) * 4;             // 4 output rows per block

    int t = threadIdx.x;
    int lane = t & 63, w = t >> 6;
    int quad = lane >> 4, l15 = lane & 15;

    __shared__ __align__(16) short win[6 * 64 * 64];      // rows y0-1..y0+4, 48 KB
    __shared__ __align__(16) short abuf[2][128 * 64];     // [o_l][slot8][8ch] 2x16 KB

    int zoff = (int)(zbuf - xt);               // halo rows redirect into zbuf

    // window staging offsets (12 rounds x 256 threads = 3072 tasks)
    int woff[12];
    #pragma unroll
    for (int r = 0; r < 12; ++r) {
        int u = r * 256 + t;
        int pos = u >> 3, sp = u & 7;
        int wrow = pos >> 6, xc = pos & 63;
        int yy = y0 - 1 + wrow;
        int ss = sp ^ (xc & 7);                 // XOR swizzle at source
        woff[r] = ((unsigned)yy < 64u)
            ? ((b * 64 + yy) * 64 + xc) * 256 + ss * 8
            : zoff;
    }
    // A staging offsets (4 rounds)
    int aoff[4];
    #pragma unroll
    for (int r = 0; r < 4; ++r) {
        int u = r * 256 + t;
        int o_l = u >> 3, sp = u & 7;
        int ss = sp ^ (o_l & 7);
        aoff[r] = ((b * 256 + o_base + o_l) * 9) * 256 + ss * 8;
    }

    int m_base = (w & 1) * 64;
    int ry0    = (w >> 1) * 2;                 // output rows {0,1} or {2,3}

    f32x4 acc[4][8];
    #pragma unroll
    for (int i = 0; i < 4; ++i)
        #pragma unroll
        for (int j = 0; j < 8; ++j) acc[i][j] = {0.f, 0.f, 0.f, 0.f};

    for (int cc = 0; cc < 4; ++cc) {
        int ccOff = cc * 64;
        // stage window + A[tap0] (prev-iteration tail barrier protects reuse)
        #pragma unroll
        for (int r = 0; r < 12; ++r)
            gll16(xt + woff[r] + ccOff, &win[(r * 256 + w * 64) * 8]);
        #pragma unroll
        for (int r = 0; r < 4; ++r)
            gll16(wcomb + aoff[r] + ccOff, &abuf[0][(r * 256 + w * 64) * 8]);
        __syncthreads();

        #pragma unroll
        for (int tap = 0; tap < 9; ++tap) {
            const int ti = tap / 3, tj = tap % 3;
            const int cur = tap & 1;
            if (tap < 8) {   // prefetch next tap's A into the other buffer
                int off2 = (tap + 1) * 256 + ccOff;
                #pragma unroll
                for (int r = 0; r < 4; ++r)
                    gll16(wcomb + aoff[r] + off2, &abuf[cur ^ 1][(r * 256 + w * 64) * 8]);
            }
            #pragma unroll
            for (int s = 0; s < 2; ++s) {
                int slog = s * 4 + quad;
                bf16x8 af[4], bv[8];
                #pragma unroll
                for (int mb = 0; mb < 4; ++mb) {
                    int o_l = m_base + mb * 16 + l15;
                    af[mb] = *(const bf16x8*)&abuf[cur][o_l * 64 + ((slog ^ (o_l & 7)) * 8)];
                }
                #pragma unroll
                for (int nb = 0; nb < 8; ++nb) {
                    int rr = nb >> 2, xq4 = nb & 3;
                    int xc = xq4 * 16 + l15 + (tj - 1);
                    bool ok = ((unsigned)xc < 64u);
                    int xs = ok ? xc : 0;
                    int wrow = ry0 + rr + ti;    // 0..5
                    bf16x8 v = *(const bf16x8*)&win[(wrow * 64 + xs) * 64
                                                    + ((slog ^ (xs & 7)) * 8)];
                    bf16x8 zz = {};
                    bv[nb] = ok ? v : zz;        // column halo is zero
                }
                __builtin_amdgcn_s_setprio(1);
                #pragma unroll
                for (int mb = 0; mb < 4; ++mb)
                    #pragma unroll
                    for (int nb = 0; nb < 8; ++nb)
                        acc[mb][nb] = __builtin_amdgcn_mfma_f32_16x16x32_bf16(
                            af[mb], bv[nb], acc[mb][nb], 0, 0, 0);
                __builtin_amdgcn_s_setprio(0);
            }
            __syncthreads();   // drains prefetch vmcnt + protects buffer swap
        }
    }

    #pragma unroll
    for (int mb = 0; mb < 4; ++mb) {
        #pragma unroll
        for (int nb = 0; nb < 8; ++nb) {
            int rr = nb >> 2, xq4 = nb & 3;
            int xx = xq4 * 16 + l15;
            int yy = y0 + ry0 + rr;
            #pragma unroll
            for (int rg = 0; rg < 4; ++rg) {
                int o = o_base + m_base + mb * 16 + quad * 4 + rg;
                out[(((size_t)b * OC_ + o) * H_ + yy) * W_ + xx] = acc[mb][nb][rg];
            }
        }
    }
}

// ---------- launcher ----------
extern "C" void kernel_launch(void* const* d_in, const int* in_sizes, int n_in,
                              void* d_out, int out_size, void* d_ws, size_t ws_size,
                              hipStream_t stream) {
    const float* x       = (const float*)d_in[0];
    const float* E       = (const float*)d_in[1];
    const float* rconv_w = (const float*)d_in[2];
    const float* rconv_b = (const float*)d_in[3];
    const float* fc_w    = (const float*)d_in[4];
    const float* fc_b    = (const float*)d_in[5];
    float* out = (float*)d_out;

    char* ws = (char*)d_ws;
    short* xt     = (short*)(ws);                    // 32 MiB
    short* wcomb  = (short*)(ws + 33554432);         // 18 MiB
    float* pooled = (float*)(ws + 52428800);         // 256 KiB
    short* zbuf   = (short*)(ws + 52690944);         // 1 KiB zeros (adjacent to pooled)
    float* rbuf   = (float*)(ws + 52692992);         // 48 KiB

    hipMemsetAsync(pooled, 0, 262144 + 1024, stream);   // pooled + zbuf in one node

    k_transpose_pool<<<dim3(64, 16), 256, 0, stream>>>(x, xt, pooled);
    k_route<<<dim3(64), 256, 0, stream>>>(pooled, rconv_w, rconv_b, fc_w, fc_b, rbuf);
    k_combine<<<dim3(256, 4), 256, 0, stream>>>(E, rbuf, wcomb);
    k_conv<<<dim3(512), 256, 0, stream>>>(xt, wcomb, out, zbuf);
}